// Round 6
// baseline (6840.058 us; speedup 1.0000x reference)
//
#include <hip/hip_runtime.h>
#include <hip/hip_bf16.h>

#define LSEQ   2048
#define NHEAD  16
#define NCHUNK 32
#define WKV_NB 32
#define SSD_NB 1024   // NBATCH*NCHUNK*NHEAD

// workspace layout (floats)
#define WS_CS 0u          // chunk states -> (after scan) entering states, (sid,p,n)
#define WS_YD 4194304u    // Y_diag f32, (b,l,h,p) == output layout
#define WS_CA 8388608u    // per-chunk inclusive cumsum of A, (sid,64)

// ---------------------------------------------------------------------------
// Fused kernel: blocks [0,32) = WKV via WY/chunked form (single wave),
//               blocks [32,1056) = SSD intra-chunk (256 threads)
// ---------------------------------------------------------------------------
__global__ __launch_bounds__(256)
void k_fused(const float* __restrict__ X, const float* __restrict__ A,
             const float* __restrict__ Bm, const float* __restrict__ Cm,
             const float* __restrict__ rg, const float* __restrict__ kg,
             const float* __restrict__ vg, const float* __restrict__ wg,
             const float* __restrict__ bg, float* __restrict__ ws,
             float* __restrict__ out)
{
    __shared__ float Bs[64][68];
    __shared__ float CsGL[64][68];
    __shared__ float Xs[64][64];
    __shared__ float cA[64], decL[64];

    const int t = threadIdx.x;

    if (blockIdx.x < WKV_NB) {
        // ================= WKV (WY form, tile T=8, one wave, lane = row i) =================
        if (t >= 64) return;                 // no __syncthreads on this path
        float* dt = &Bs[0][0];               // [64][8] delta staging (dt[j*8+s] = delta_s[j])
        float* kt = &CsGL[0][0];             // [64][8] next-tile k  (kt[j*8+u] = k'_u[j])

        const int bh = blockIdx.x;
        const int b  = bh >> 4, h = bh & 15;
        const int lane = t;
        const size_t base = (size_t)bh * LSEQ * 64 + lane;
        const float* pr = rg + base;
        const float* pk = kg + base;
        const float* pv = vg + base;
        const float* pw = wg + base;
        const float* pb = bg + base;
        float* pout = out + ((size_t)b * LSEQ * NHEAD + h) * 64 + lane;

        float st[64];                        // true state row: S[lane][j]
        #pragma unroll
        for (int j = 0; j < 64; j++) st[j] = 0.f;

        float c[8], acc[8];                  // c_u = (S_0 k_u)[lane]; acc_u = sum_{s<u} g_s m_su
        #pragma unroll
        for (int u = 0; u < 8; u++) { c[u] = 0.f; acc[u] = 0.f; }

        // current-tile regs + fixed prefetch regs (STATIC names only)
        float R[8], K[8], V[8], W[8], Bb[8];
        float nR[8], nK[8], nV[8], nW[8], nB[8];

        auto pref = [&](int tb) {
            #pragma unroll
            for (int u = 0; u < 8; u++) {
                size_t o = (size_t)(tb + u) * 64;
                nR[u] = pr[o]; nK[u] = pk[o]; nV[u] = pv[o];
                nW[u] = pw[o]; nB[u] = pb[o];
            }
        };
        auto commit = [&]() {
            #pragma unroll
            for (int u = 0; u < 8; u++) {
                R[u] = nR[u]; K[u] = nK[u]; V[u] = nV[u]; W[u] = nW[u]; Bb[u] = nB[u];
            }
        };

        pref(0); commit(); pref(8);

        for (int t0 = 0; t0 < LSEQ; t0 += 8) {
            // tile-local cumulative decay + ghat coefficients (all per-lane)
            float Wc[8], g[8];
            Wc[0] = W[0];
            #pragma unroll
            for (int u = 1; u < 8; u++) Wc[u] = Wc[u-1] * W[u];
            #pragma unroll
            for (int u = 0; u < 8; u++)
                g[u] = Bb[u] * K[u] * __builtin_amdgcn_rcpf(Wc[u]);

            float dlt[8];
            // -------- serial steps: scalars only on the chain --------
            #pragma unroll
            for (int s = 0; s < 8; s++) {
                float pre   = c[s] + acc[s];
                float wf    = (s == 0) ? 1.f : Wc[s-1];
                float delta = V[s] - wf * pre;
                dlt[s] = delta;
                // m_su = <delta_s, k_u> for u=s..7 via packed butterfly
                float m[8];
                #pragma unroll
                for (int u = s; u < 8; u++) m[u] = delta * K[u];
                #pragma unroll
                for (int off = 1; off < 64; off <<= 1) {
                    #pragma unroll
                    for (int u = s; u < 8; u++) m[u] += __shfl_xor(m[u], off, 64);
                }
                // y_s = r * Wc_s * (c_s + acc_s + g_s * m_ss)
                pout[(size_t)(t0 + s) * (NHEAD * 64)] =
                    R[s] * (Wc[s] * (pre + g[s] * m[s]));
                #pragma unroll
                for (int u = s + 1; u < 8; u++) acc[u] += g[s] * m[u];
            }

            if (t0 + 8 < LSEQ) {
                // -------- stage deltas + next-tile k, fold state, next c --------
                __builtin_amdgcn_wave_barrier();
                *(float4*)&kt[lane * 8]     = make_float4(nK[0], nK[1], nK[2], nK[3]);
                *(float4*)&kt[lane * 8 + 4] = make_float4(nK[4], nK[5], nK[6], nK[7]);
                *(float4*)&dt[lane * 8]     = make_float4(dlt[0], dlt[1], dlt[2], dlt[3]);
                *(float4*)&dt[lane * 8 + 4] = make_float4(dlt[4], dlt[5], dlt[6], dlt[7]);
                __builtin_amdgcn_wave_barrier();

                const float w7 = Wc[7];
                #pragma unroll
                for (int u = 0; u < 8; u++) { c[u] = 0.f; acc[u] = 0.f; }
                #pragma unroll
                for (int j = 0; j < 64; j++) {   // fully unrolled: st[j] static
                    float4 d0 = *(const float4*)&dt[j * 8];
                    float4 d1 = *(const float4*)&dt[j * 8 + 4];
                    float4 k0 = *(const float4*)&kt[j * 8];
                    float4 k1 = *(const float4*)&kt[j * 8 + 4];
                    float sj = st[j]
                        + g[0]*d0.x + g[1]*d0.y + g[2]*d0.z + g[3]*d0.w
                        + g[4]*d1.x + g[5]*d1.y + g[6]*d1.z + g[7]*d1.w;
                    sj *= w7;
                    st[j] = sj;
                    c[0] += sj*k0.x; c[1] += sj*k0.y; c[2] += sj*k0.z; c[3] += sj*k0.w;
                    c[4] += sj*k1.x; c[5] += sj*k1.y; c[6] += sj*k1.z; c[7] += sj*k1.w;
                }
                commit();
                if (t0 + 16 < LSEQ) pref(t0 + 16);
            }
        }
        return;
    }

    // ================= SSD intra-chunk (unchanged from R5) =================
    const int sid = blockIdx.x - WKV_NB;
    const int b = sid >> 9;
    const int c = (sid >> 4) & 31;
    const int h = sid & 15;
    const size_t rowbase = ((size_t)(b * LSEQ + c * 64) * NHEAD + h) * 64;
    const int rstride = NHEAD * 64;   // 1024

    #pragma unroll
    for (int i = 0; i < 4; i++) {
        int fl = t + 256 * i; int row = fl >> 4; int c4 = fl & 15;
        size_t go = rowbase + (size_t)row * rstride;
        float4 xv = ((const float4*)(X  + go))[c4];
        float4 bv = ((const float4*)(Bm + go))[c4];
        float4 cv = ((const float4*)(Cm + go))[c4];
        *(float4*)&Xs[row][c4 * 4]   = xv;
        *(float4*)&Bs[row][c4 * 4]   = bv;
        *(float4*)&CsGL[row][c4 * 4] = cv;
    }
    if (t < 64) {
        float a = A[(size_t)(b * LSEQ + c * 64 + t) * NHEAD + h];
        float s = a;
        #pragma unroll
        for (int off = 1; off < 64; off <<= 1) {
            float nv = __shfl_up(s, off, 64);
            if (t >= off) s += nv;
        }
        cA[t] = s;
        ws[WS_CA + (size_t)sid * 64 + t] = s;
        float tot = __shfl(s, 63, 64);
        decL[t] = expf(tot - s);
    }
    __syncthreads();

    const int l = t >> 2;
    const int q = t & 3;

    float g[16];
    {
        float acc[16];
        #pragma unroll
        for (int si = 0; si < 16; si++) acc[si] = 0.f;
        #pragma unroll
        for (int n4 = 0; n4 < 16; n4++) {
            float4 cv = *(const float4*)&CsGL[l][n4 * 4];
            #pragma unroll
            for (int si = 0; si < 16; si++) {
                float4 bv = *(const float4*)&Bs[q + 4 * si][n4 * 4];
                acc[si] += cv.x * bv.x + cv.y * bv.y + cv.z * bv.z + cv.w * bv.w;
            }
        }
        float cl = cA[l];
        #pragma unroll
        for (int si = 0; si < 16; si++) {
            int s = q + 4 * si;
            g[si] = (s <= l) ? acc[si] * expf(cl - cA[s]) : 0.f;
        }
    }
    __syncthreads();
    #pragma unroll
    for (int si = 0; si < 16; si++) CsGL[l][q + 4 * si] = g[si];
    __syncthreads();

    {
        const int pb = q * 16;
        float4 acc[4];
        #pragma unroll
        for (int i = 0; i < 4; i++) acc[i] = make_float4(0.f, 0.f, 0.f, 0.f);
        for (int s = 0; s < 64; s++) {
            float gv = CsGL[l][s];
            #pragma unroll
            for (int i = 0; i < 4; i++) {
                float4 xv = *(const float4*)&Xs[s][pb + 4 * i];
                acc[i].x += gv * xv.x; acc[i].y += gv * xv.y;
                acc[i].z += gv * xv.z; acc[i].w += gv * xv.w;
            }
        }
        size_t o = rowbase + (size_t)l * rstride + pb;
        float* yd = ws + WS_YD;
        #pragma unroll
        for (int i = 0; i < 4; i++) ((float4*)(yd + o))[i] = acc[i];
    }

    {
        const int p  = l;
        const int nb = q * 16;
        float4 acc[4];
        #pragma unroll
        for (int i = 0; i < 4; i++) acc[i] = make_float4(0.f, 0.f, 0.f, 0.f);
        for (int l2 = 0; l2 < 64; l2++) {
            float cf = decL[l2] * Xs[l2][p];
            #pragma unroll
            for (int i = 0; i < 4; i++) {
                float4 bv = *(const float4*)&Bs[l2][nb + 4 * i];
                acc[i].x += cf * bv.x; acc[i].y += cf * bv.y;
                acc[i].z += cf * bv.z; acc[i].w += cf * bv.w;
            }
        }
        float* cs = ws + WS_CS + (size_t)sid * 4096 + (size_t)p * 64 + nb;
        #pragma unroll
        for (int i = 0; i < 4; i++) ((float4*)cs)[i] = acc[i];
    }
}

// ---------------------------------------------------------------------------
// K2: inter-chunk scan per (b,h): overwrite cs_c with state ENTERING chunk c
// ---------------------------------------------------------------------------
__global__ __launch_bounds__(256)
void k_scan(float* __restrict__ ws)
{
    const int t = threadIdx.x;
    const int b = blockIdx.x >> 4;
    const int h = blockIdx.x & 15;
    float prev[16];
    #pragma unroll
    for (int qq = 0; qq < 16; qq++) prev[qq] = 0.f;
    for (int c = 0; c < NCHUNK; c++) {
        const int sid = b * 512 + c * 16 + h;
        float dec = expf(ws[WS_CA + (size_t)sid * 64 + 63]);
        float* cs = ws + WS_CS + (size_t)sid * 4096;
        float tmp[16];
        #pragma unroll
        for (int qq = 0; qq < 16; qq++) tmp[qq] = cs[t + 256 * qq];
        #pragma unroll
        for (int qq = 0; qq < 16; qq++) cs[t + 256 * qq] = prev[qq];
        #pragma unroll
        for (int qq = 0; qq < 16; qq++) prev[qq] = prev[qq] * dec + tmp[qq];
    }
}

// ---------------------------------------------------------------------------
// K3: out = Y_diag + exp(cumA[l]) * C_l . state^T + out(=wkv)    (all f32)
// ---------------------------------------------------------------------------
__global__ __launch_bounds__(256)
void k_yoff(const float* __restrict__ Cm, const float* __restrict__ ws,
            float* __restrict__ out)
{
    __shared__ float Cs[64][68];
    __shared__ float ST[64][68];   // ST[n][p] = state[p][n]
    __shared__ float dout[64];
    const int t = threadIdx.x;
    const int sid = blockIdx.x;
    const int b = sid >> 9;
    const int c = (sid >> 4) & 31;
    const int h = sid & 15;
    const size_t rowbase = ((size_t)(b * LSEQ + c * 64) * NHEAD + h) * 64;
    const int rstride = NHEAD * 64;

    #pragma unroll
    for (int i = 0; i < 4; i++) {
        int fl = t + 256 * i; int row = fl >> 4; int c4 = fl & 15;
        float4 cv = ((const float4*)(Cm + rowbase + (size_t)row * rstride))[c4];
        *(float4*)&Cs[row][c4 * 4] = cv;
        float4 sv = ((const float4*)(ws + WS_CS + (size_t)sid * 4096 + (size_t)row * 64))[c4];
        ST[c4 * 4 + 0][row] = sv.x;
        ST[c4 * 4 + 1][row] = sv.y;
        ST[c4 * 4 + 2][row] = sv.z;
        ST[c4 * 4 + 3][row] = sv.w;
    }
    if (t < 64) dout[t] = expf(ws[WS_CA + (size_t)sid * 64 + t]);
    __syncthreads();

    const int l  = t >> 2;
    const int pb = (t & 3) * 16;
    float4 acc[4];
    #pragma unroll
    for (int i = 0; i < 4; i++) acc[i] = make_float4(0.f, 0.f, 0.f, 0.f);
    for (int n = 0; n < 64; n++) {
        float cv = Cs[l][n];
        #pragma unroll
        for (int i = 0; i < 4; i++) {
            float4 sv = *(const float4*)&ST[n][pb + 4 * i];
            acc[i].x += cv * sv.x; acc[i].y += cv * sv.y;
            acc[i].z += cv * sv.z; acc[i].w += cv * sv.w;
        }
    }
    const float sc = dout[l];
    const size_t o = rowbase + (size_t)l * rstride + pb;
    #pragma unroll
    for (int i = 0; i < 4; i++) {
        float4 yd = ((const float4*)(ws + WS_YD + o))[i];
        float4 yw = ((const float4*)(out + o))[i];
        float4 res;
        res.x = yd.x + sc * acc[i].x + yw.x;
        res.y = yd.y + sc * acc[i].y + yw.y;
        res.z = yd.z + sc * acc[i].z + yw.z;
        res.w = yd.w + sc * acc[i].w + yw.w;
        ((float4*)(out + o))[i] = res;
    }
}

extern "C" void kernel_launch(void* const* d_in, const int* in_sizes, int n_in,
                              void* d_out, int out_size, void* d_ws, size_t ws_size,
                              hipStream_t stream)
{
    const float* X  = (const float*)d_in[0];
    const float* A  = (const float*)d_in[1];
    const float* Bm = (const float*)d_in[2];
    const float* Cm = (const float*)d_in[3];
    const float* r  = (const float*)d_in[4];
    const float* k  = (const float*)d_in[5];
    const float* v  = (const float*)d_in[6];
    const float* w  = (const float*)d_in[7];
    const float* bo = (const float*)d_in[8];
    float* ws = (float*)d_ws;
    float* out = (float*)d_out;

    hipLaunchKernelGGL(k_fused, dim3(WKV_NB + SSD_NB), dim3(256), 0, stream,
                       X, A, Bm, Cm, r, k, v, w, bo, ws, out);
    hipLaunchKernelGGL(k_scan, dim3(32),     dim3(256), 0, stream, ws);
    hipLaunchKernelGGL(k_yoff, dim3(SSD_NB), dim3(256), 0, stream, Cm, ws, out);
}